// Round 1
// 371.803 us; speedup vs baseline: 1.0054x; 1.0054x over previous
//
#include <hip/hip_runtime.h>

// PerformerAttnBlock — Round 5: 256x256 8-wave deep-pipelined GEMMs
// (T3 counted-vmcnt + T4 + T5 setprio + existing T2 swizzle + T1 XCD swizzle).
// B=4, IN=512, T=4096, EMBED=1024, H=16, D=64, F=256.
// WS (bytes):
//   0         QKVb bf16 [16384][3072] (96MB)
//   100663296 attnb bf16 [16384][1024] (32MB)  -- Abuf bf16 [16384][512] aliases pre-gemm1
//   134217728 Btqkv bf16 [3072][512] (3MB)
//   137363456 WoT bf16 [1024][1024] (2MB)
//   139460608 projb bf16 [256][64] (32KB)
//   139493376 KVg fp32 [64][256][64] (4MB)
//   143687680 Ksumg fp32 [64][256] (64KB)
//   143753216 KVTb bf16 [64][64][256] (2MB)

constexpr int kB  = 4;
constexpr int kIn = 512;
constexpr int kT  = 4096;
constexpr int kE  = 1024;
constexpr int kH  = 16;
constexpr int kD  = 64;
constexpr int kF  = 256;
constexpr int kQKVs = 3072;

typedef __attribute__((ext_vector_type(8))) short bf16x8;
typedef __attribute__((ext_vector_type(4))) float f32x4;

__device__ __forceinline__ unsigned short f2bf(float f) {
    unsigned u = __float_as_uint(f);
    u += 0x7fff + ((u >> 16) & 1);          // RNE
    return (unsigned short)(u >> 16);
}
__device__ __forceinline__ float bf2f(unsigned short s) {
    return __uint_as_float(((unsigned)s) << 16);
}
__device__ __forceinline__ void gload_lds16(const void* g, void* l) {
    __builtin_amdgcn_global_load_lds((const __attribute__((address_space(1))) void*)g,
                                     (__attribute__((address_space(3))) void*)l, 16, 0, 0);
}

// ---------------------------------------------------------------- zero
__global__ __launch_bounds__(256) void zero_kernel(float* __restrict__ p, int n) {
    int i = blockIdx.x * 256 + threadIdx.x;
    if (i < n) p[i] = 0.f;
}

// ---------------------------------------------------------------- copy x -> out[:, :512, :]
__global__ __launch_bounds__(256) void copy_x_kernel(const float* __restrict__ x,
                                                     float* __restrict__ out) {
    const int perB4 = kIn * kT / 4;
    int idx = blockIdx.x * 256 + threadIdx.x;
    if (idx < kB * perB4) {
        int b = idx / perB4, e = idx % perB4;
        ((float4*)out)[(size_t)b * ((kIn + kE) * kT / 4) + e] = ((const float4*)x)[idx];
    }
}

// ---------------------------------------------------------------- flat fp32->bf16
__global__ __launch_bounds__(256) void f2b_flat_kernel(const float* __restrict__ s,
                                                       unsigned short* __restrict__ d, int n4) {
    int i = blockIdx.x * 256 + threadIdx.x;
    if (i < n4) {
        float4 v = ((const float4*)s)[i];
        ushort4 o;
        o.x = f2bf(v.x); o.y = f2bf(v.y); o.z = f2bf(v.z); o.w = f2bf(v.w);
        ((ushort4*)d)[i] = o;
    }
}

// ---------------------------------------------------------------- transpose + fp32->bf16
// src [R][C] fp32 (+z*sstride), dst [C][R] bf16 (+z*dstride)
__global__ __launch_bounds__(256) void trans_f2b_kernel(const float* __restrict__ src,
                                                        unsigned short* __restrict__ dst,
                                                        int R, int C,
                                                        long sstride, long dstride) {
    __shared__ float L[64][68];
    src += (size_t)blockIdx.z * sstride;
    dst += (size_t)blockIdx.z * dstride;
    const int c0 = blockIdx.x * 64, r0 = blockIdx.y * 64;
    const int tid = threadIdx.x;
#pragma unroll
    for (int it = 0; it < 4; ++it) {
        int lin = it * 256 + tid;
        int i = lin >> 4;
        int j4 = (lin & 15) * 4;
        float4 v = *(const float4*)(src + (size_t)(r0 + i) * C + c0 + j4);
        L[j4 + 0][i] = v.x; L[j4 + 1][i] = v.y; L[j4 + 2][i] = v.z; L[j4 + 3][i] = v.w;
    }
    __syncthreads();
#pragma unroll
    for (int it = 0; it < 4; ++it) {
        int lin = it * 256 + tid;
        int cc = lin >> 4;
        int r4 = (lin & 15) * 4;
        ushort4 o;
        o.x = f2bf(L[cc][r4 + 0]); o.y = f2bf(L[cc][r4 + 1]);
        o.z = f2bf(L[cc][r4 + 2]); o.w = f2bf(L[cc][r4 + 3]);
        *(ushort4*)(dst + (size_t)(c0 + cc) * R + r0 + r4) = o;
    }
}

// ---------------------------------------------------------------- fused Wq/Wk/Wv transpose
__global__ __launch_bounds__(256) void trans_qkv_kernel(const float* __restrict__ Wq,
                                                        const float* __restrict__ Wk,
                                                        const float* __restrict__ Wv,
                                                        unsigned short* __restrict__ dst) {
    __shared__ float L[64][68];
    const int z = blockIdx.z;
    const float* src = (z == 0) ? Wq : (z == 1) ? Wk : Wv;
    dst += (size_t)z * kE * kIn;
    const int c0 = blockIdx.x * 64, r0 = blockIdx.y * 64;   // c over E, r over In
    const int tid = threadIdx.x;
#pragma unroll
    for (int it = 0; it < 4; ++it) {
        int lin = it * 256 + tid;
        int i = lin >> 4;
        int j4 = (lin & 15) * 4;
        float4 v = *(const float4*)(src + (size_t)(r0 + i) * kE + c0 + j4);
        L[j4 + 0][i] = v.x; L[j4 + 1][i] = v.y; L[j4 + 2][i] = v.z; L[j4 + 3][i] = v.w;
    }
    __syncthreads();
#pragma unroll
    for (int it = 0; it < 4; ++it) {
        int lin = it * 256 + tid;
        int cc = lin >> 4;
        int r4 = (lin & 15) * 4;
        ushort4 o;
        o.x = f2bf(L[cc][r4 + 0]); o.y = f2bf(L[cc][r4 + 1]);
        o.z = f2bf(L[cc][r4 + 2]); o.w = f2bf(L[cc][r4 + 3]);
        *(ushort4*)(dst + (size_t)(c0 + cc) * kIn + r0 + r4) = o;
    }
}

// ================================================================ 256x256 pipelined GEMM core
// 512 threads = 8 waves (2M x 4N); per-wave output 128x64 (acc[8][4] f32x4).
// LDS: 2 x (A[256][64] + B[256][64]) bf16 = 128KB, XOR chunk-swizzled.
// Pipeline: tile t+2 staged (8 gload_lds/wave) right after buf[t&1] is freed;
// boundary wait = vmcnt(8) (tile t+1 landed, t+2's 8 still in flight).
__device__ __forceinline__ void stage256(const unsigned short* __restrict__ A,
                                         const unsigned short* __restrict__ Bt,
                                         int K, int m0, int n0, int kt,
                                         unsigned short* AsB, unsigned short* BsB,
                                         int tid) {
    const int w = tid >> 6;
    const size_t k0 = (size_t)kt * 64;
#pragma unroll
    for (int r = 0; r < 4; ++r) {
        int idx = r * 512 + tid;
        int row = idx >> 3;
        int cg = (idx & 7) ^ (row & 7);                  // pre-swizzled global source chunk
        gload_lds16(A + (size_t)(m0 + row) * K + k0 + cg * 8, AsB + r * 4096 + w * 512);
    }
#pragma unroll
    for (int r = 0; r < 4; ++r) {
        int idx = r * 512 + tid;
        int row = idx >> 3;
        int cg = (idx & 7) ^ (row & 7);
        gload_lds16(Bt + (size_t)(n0 + row) * K + k0 + cg * 8, BsB + r * 4096 + w * 512);
    }
}

__device__ __forceinline__ void gemm256_mainloop(const unsigned short* __restrict__ A,
                                                 const unsigned short* __restrict__ Bt,
                                                 int K, int m0, int n0,
                                                 unsigned short* smem,
                                                 f32x4 (&acc)[8][4]) {
    const int tid = threadIdx.x, lane = tid & 63, w = tid >> 6;
    const int col = lane & 15, quad = lane >> 4;
    const int wm = (w >> 2) * 128, wn = (w & 3) * 64;
    const int swz = col & 7;
    const int nt = K >> 6;
    unsigned short* As0 = smem;
    unsigned short* As1 = smem + 16384;
    unsigned short* Bs0 = smem + 32768;
    unsigned short* Bs1 = smem + 49152;

    stage256(A, Bt, K, m0, n0, 0, As0, Bs0, tid);
    stage256(A, Bt, K, m0, n0, 1, As1, Bs1, tid);
#pragma unroll
    for (int i = 0; i < 8; ++i)
#pragma unroll
        for (int j = 0; j < 4; ++j) acc[i][j] = (f32x4){0.f, 0.f, 0.f, 0.f};
    asm volatile("s_waitcnt vmcnt(8)" ::: "memory");     // tile 0 landed; tile 1 in flight
    __builtin_amdgcn_s_barrier();
    __builtin_amdgcn_sched_barrier(0);

    for (int t = 0; ; ++t) {
        const unsigned short* As_ = (t & 1) ? As1 : As0;
        const unsigned short* Bs_ = (t & 1) ? Bs1 : Bs0;
        // 4 phases: one 64x32 C-quadrant x K=64 each (16 MFMA)
#pragma unroll
        for (int q = 0; q < 4; ++q) {
            const int ar0 = wm + (q >> 1) * 64;
            const int bc0 = wn + (q & 1) * 32;
            bf16x8 av[2][4], bv[2][2];
#pragma unroll
            for (int s = 0; s < 2; ++s) {
                const int kc = ((s * 4 + quad) ^ swz) * 8;
#pragma unroll
                for (int i = 0; i < 4; ++i)
                    av[s][i] = *(const bf16x8*)&As_[(ar0 + i * 16 + col) * 64 + kc];
#pragma unroll
                for (int j = 0; j < 2; ++j)
                    bv[s][j] = *(const bf16x8*)&Bs_[(bc0 + j * 16 + col) * 64 + kc];
            }
            __builtin_amdgcn_s_setprio(1);
#pragma unroll
            for (int s = 0; s < 2; ++s)
#pragma unroll
                for (int i = 0; i < 4; ++i)
#pragma unroll
                    for (int j = 0; j < 2; ++j)
                        acc[(q >> 1) * 4 + i][(q & 1) * 2 + j] =
                            __builtin_amdgcn_mfma_f32_16x16x32_bf16(
                                av[s][i], bv[s][j],
                                acc[(q >> 1) * 4 + i][(q & 1) * 2 + j], 0, 0, 0);
            __builtin_amdgcn_s_setprio(0);
            __builtin_amdgcn_sched_barrier(0);
            __builtin_amdgcn_s_barrier();
            __builtin_amdgcn_sched_barrier(0);
        }
        if (t == nt - 1) break;
        if (t + 2 < nt) {
            // buf[t&1] free (phase-4 barrier passed) -> stage tile t+2 into it
            stage256(A, Bt, K, m0, n0, t + 2, (t & 1) ? As1 : As0, (t & 1) ? Bs1 : Bs0, tid);
            asm volatile("s_waitcnt vmcnt(8)" ::: "memory");   // tile t+1 landed
        } else {
            asm volatile("s_waitcnt vmcnt(0)" ::: "memory");   // drain last tile
        }
        __builtin_amdgcn_sched_barrier(0);
        __builtin_amdgcn_s_barrier();
        __builtin_amdgcn_sched_barrier(0);
    }
}

// ---------------------------------------------------------------- GEMM1: bf16 out
__global__ __launch_bounds__(512) void gemm256_b16(const unsigned short* __restrict__ A,
                                                   const unsigned short* __restrict__ Bt,
                                                   unsigned short* __restrict__ C,
                                                   int N, int K, int ntN) {
    extern __shared__ unsigned short smem_us[];
    const int tid = threadIdx.x, lane = tid & 63, w = tid >> 6;
    const int col = lane & 15, quad = lane >> 4;
    const int wm = (w >> 2) * 128, wn = (w & 3) * 64;
    // XCD-chunked bijective swizzle (gridDim.x % 8 == 0)
    const int bid = blockIdx.x;
    const int qch = gridDim.x >> 3;
    const int swb = (bid & 7) * qch + (bid >> 3);
    const int mt = swb / ntN, ntl = swb - mt * ntN;
    const int m0 = mt * 256, n0 = ntl * 256;

    f32x4 acc[8][4];
    gemm256_mainloop(A, Bt, K, m0, n0, smem_us, acc);

    // epilogue: per-wave LDS repack (reuses smem; all waves past final barrier)
    float* Tw = (float*)smem_us + w * 336;
    const int t2 = lane >> 2, n4 = (lane & 3) * 4;
#pragma unroll
    for (int ri = 0; ri < 8; ++ri)
#pragma unroll
        for (int cj = 0; cj < 4; ++cj) {
#pragma unroll
            for (int r = 0; r < 4; ++r)
                Tw[(quad * 4 + r) * 20 + col] = acc[ri][cj][r];
            float4 v = *(const float4*)&Tw[t2 * 20 + n4];
            ushort4 o;
            o.x = f2bf(v.x); o.y = f2bf(v.y); o.z = f2bf(v.z); o.w = f2bf(v.w);
            *(ushort4*)(C + (size_t)(m0 + wm + ri * 16 + t2) * N + n0 + wn + cj * 16 + n4) = o;
        }
}

// ---------------------------------------------------------------- GEMM2: attn @ Wo, fp32 transposed out
__global__ __launch_bounds__(512) void gemm256_out(const unsigned short* __restrict__ A,
                                                   const unsigned short* __restrict__ Bt,
                                                   float* __restrict__ out,
                                                   int N, int K, int ntN) {
    extern __shared__ unsigned short smem_us[];
    const int tid = threadIdx.x, lane = tid & 63, w = tid >> 6;
    const int col = lane & 15, quad = lane >> 4;
    const int wm = (w >> 2) * 128, wn = (w & 3) * 64;
    const int bid = blockIdx.x;
    const int qch = gridDim.x >> 3;
    const int swb = (bid & 7) * qch + (bid >> 3);
    const int mt = swb / ntN, ntl = swb - mt * ntN;
    const int m0 = mt * 256, n0 = ntl * 256;

    f32x4 acc[8][4];
    gemm256_mainloop(A, Bt, K, m0, n0, smem_us, acc);

    // epilogue: transpose per 16x16 fragment in per-wave LDS, store out[n][t] coalesced
    const int b = m0 >> 12, t0 = m0 & 4095;
    float* dst = out + (size_t)b * (kIn + kE) * kT + (size_t)kIn * kT;
    float* Tw = (float*)smem_us + w * 336;
    const int n2 = lane >> 2, t4 = (lane & 3) * 4;
#pragma unroll
    for (int ri = 0; ri < 8; ++ri)
#pragma unroll
        for (int cj = 0; cj < 4; ++cj) {
            *(float4*)&Tw[col * 20 + quad * 4] =
                (float4){acc[ri][cj][0], acc[ri][cj][1], acc[ri][cj][2], acc[ri][cj][3]};
            float4 v = *(const float4*)&Tw[n2 * 20 + t4];
            *(float4*)(dst + (size_t)(n0 + wn + cj * 16 + n2) * kT + t0 + wm + ri * 16 + t4) = v;
        }
}

// ---------------------------------------------------------------- Phase A (MFMA): KV, Ksum
__global__ __launch_bounds__(256) void phaseA_mfma(const unsigned short* __restrict__ QKVb,
                                                   const unsigned short* __restrict__ projb,
                                                   float* __restrict__ KVg,
                                                   float* __restrict__ Ksumg) {
    __shared__ unsigned short Ks[64 * 64];     // [t][d] XOR-swizzled chunks
    __shared__ unsigned short VT[64 * 72];     // [d][t] pad 8
    __shared__ unsigned short KpT[256 * 72];   // [f][t] pad 8
    const int tid = threadIdx.x, lane = tid & 63, w = tid >> 6;
    const int col = lane & 15, quad = lane >> 4;
    const int bh = blockIdx.x, b = bh >> 4, h = bh & 15;
    const int grp = blockIdx.y;
    const int f0 = w * 64;
    const int swz = col & 7;

    bf16x8 bB[2][4];   // proj B-fragments, invariant
#pragma unroll
    for (int s = 0; s < 2; ++s)
#pragma unroll
        for (int j = 0; j < 4; ++j)
            bB[s][j] = *(const bf16x8*)(projb + (size_t)(f0 + j * 16 + col) * 64 + s * 32 + quad * 8);

    f32x4 kvacc[4][4];
#pragma unroll
    for (int i = 0; i < 4; ++i)
#pragma unroll
        for (int j = 0; j < 4; ++j) kvacc[i][j] = (f32x4){0.f, 0.f, 0.f, 0.f};
    float ksum_acc[4] = {0.f, 0.f, 0.f, 0.f};

    for (int it = 0; it < 8; ++it) {
        const size_t rowbase = (size_t)(b * kT + grp * 512 + it * 64) * kQKVs + h * kD;
        __syncthreads();
#pragma unroll
        for (int i2 = 0; i2 < 2; ++i2) {
            int p = (i2 * 4 + w) * 64 + lane;
            int row = p >> 3;
            int cg = ((p & 7) ^ (row & 7)) * 8;
            gload_lds16(QKVb + rowbase + 1024 + (size_t)row * kQKVs + cg, &Ks[(i2 * 4 + w) * 512]);
        }
#pragma unroll
        for (int r = 0; r < 4; ++r) {
            int lin = r * 256 + tid;
            int t = lin >> 4, d4 = (lin & 15) * 4;
            ushort4 v = *(const ushort4*)(QKVb + rowbase + 2048 + (size_t)t * kQKVs + d4);
            VT[(d4 + 0) * 72 + t] = v.x; VT[(d4 + 1) * 72 + t] = v.y;
            VT[(d4 + 2) * 72 + t] = v.z; VT[(d4 + 3) * 72 + t] = v.w;
        }
        __syncthreads();
        bf16x8 av[2][4];
#pragma unroll
        for (int s = 0; s < 2; ++s)
#pragma unroll
            for (int i = 0; i < 4; ++i)
                av[s][i] = *(const bf16x8*)&Ks[(i * 16 + col) * 64 + ((s * 4 + quad) ^ swz) * 8];
#pragma unroll
        for (int j = 0; j < 4; ++j) {
            f32x4 sa[4];
#pragma unroll
            for (int i = 0; i < 4; ++i) sa[i] = (f32x4){0.f, 0.f, 0.f, 0.f};
#pragma unroll
            for (int s = 0; s < 2; ++s)
#pragma unroll
                for (int i = 0; i < 4; ++i)
                    sa[i] = __builtin_amdgcn_mfma_f32_16x16x32_bf16(av[s][i], bB[s][j], sa[i], 0, 0, 0);
            const int f = f0 + j * 16 + col;
#pragma unroll
            for (int i = 0; i < 4; ++i) {
                float e0 = __expf(sa[i][0]) + 1e-6f;
                float e1 = __expf(sa[i][1]) + 1e-6f;
                float e2 = __expf(sa[i][2]) + 1e-6f;
                float e3 = __expf(sa[i][3]) + 1e-6f;
                ksum_acc[j] += (e0 + e1) + (e2 + e3);
                ushort4 pk;
                pk.x = f2bf(e0); pk.y = f2bf(e1); pk.z = f2bf(e2); pk.w = f2bf(e3);
                *(ushort4*)&KpT[f * 72 + i * 16 + quad * 4] = pk;
            }
        }
#pragma unroll
        for (int s = 0; s < 2; ++s) {
            const int kc = s * 32 + quad * 8;
            bf16x8 a2[4], b2[4];
#pragma unroll
            for (int i = 0; i < 4; ++i)
                a2[i] = *(const bf16x8*)&KpT[(f0 + i * 16 + col) * 72 + kc];
#pragma unroll
            for (int jn = 0; jn < 4; ++jn)
                b2[jn] = *(const bf16x8*)&VT[(jn * 16 + col) * 72 + kc];
#pragma unroll
            for (int i = 0; i < 4; ++i)
#pragma unroll
                for (int jn = 0; jn < 4; ++jn)
                    kvacc[i][jn] = __builtin_amdgcn_mfma_f32_16x16x32_bf16(a2[i], b2[jn], kvacc[i][jn], 0, 0, 0);
        }
    }
    const size_t kvbase = (size_t)bh * (kF * kD);
#pragma unroll
    for (int i = 0; i < 4; ++i)
#pragma unroll
        for (int jn = 0; jn < 4; ++jn)
#pragma unroll
            for (int r = 0; r < 4; ++r)
                atomicAdd(&KVg[kvbase + (size_t)(f0 + i * 16 + quad * 4 + r) * kD + jn * 16 + col],
                          kvacc[i][jn][r]);
#pragma unroll
    for (int j = 0; j < 4; ++j) {
        float v = ksum_acc[j];
        v += __shfl_xor(v, 16);
        v += __shfl_xor(v, 32);
        if (quad == 0) atomicAdd(&Ksumg[(size_t)bh * kF + f0 + j * 16 + col], v);
    }
}

// ---------------------------------------------------------------- Phase B (MFMA): attn bf16
__global__ __launch_bounds__(256) void phaseB_mfma(const unsigned short* __restrict__ QKVb,
                                                   const unsigned short* __restrict__ projb,
                                                   const unsigned short* __restrict__ KVTb,
                                                   const float* __restrict__ Ksumg,
                                                   unsigned short* __restrict__ attnb) {
    __shared__ unsigned short Qs[64 * 64];      // [t][d] XOR-swizzled chunks
    __shared__ unsigned short Qp[64 * 264];     // [t][f] pad 8
    __shared__ unsigned short KVTs[64 * 264];   // [d][f] pad 8
    __shared__ float KsS[256];
    __shared__ float denp[4][64];
    const int tid = threadIdx.x, lane = tid & 63, w = tid >> 6;
    const int col = lane & 15, quad = lane >> 4;
    const int bh = blockIdx.x, b = bh >> 4, h = bh & 15;
    const int grp = blockIdx.y;
    const int f0 = w * 64;
    const int swz = col & 7;

    bf16x8 bB[2][4];
#pragma unroll
    for (int s = 0; s < 2; ++s)
#pragma unroll
        for (int j = 0; j < 4; ++j)
            bB[s][j] = *(const bf16x8*)(projb + (size_t)(f0 + j * 16 + col) * 64 + s * 32 + quad * 8);

#pragma unroll
    for (int r = 0; r < 8; ++r) {
        int lin = r * 256 + tid;
        int d = lin >> 5, fc8 = (lin & 31) * 8;
        *(bf16x8*)&KVTs[d * 264 + fc8] = *(const bf16x8*)(KVTb + (size_t)bh * 16384 + d * 256 + fc8);
    }
    KsS[tid] = Ksumg[(size_t)bh * kF + tid];

    for (int it = 0; it < 8; ++it) {
        const int tg0 = grp * 512 + it * 64;
        const size_t rowbase = (size_t)(b * kT + tg0) * kQKVs + h * kD;
        __syncthreads();
#pragma unroll
        for (int i2 = 0; i2 < 2; ++i2) {
            int p = (i2 * 4 + w) * 64 + lane;
            int row = p >> 3;
            int cg = ((p & 7) ^ (row & 7)) * 8;
            gload_lds16(QKVb + rowbase + (size_t)row * kQKVs + cg, &Qs[(i2 * 4 + w) * 512]);
        }
        __syncthreads();
        bf16x8 av[2][4];
#pragma unroll
        for (int s = 0; s < 2; ++s)
#pragma unroll
            for (int i = 0; i < 4; ++i)
                av[s][i] = *(const bf16x8*)&Qs[(i * 16 + col) * 64 + ((s * 4 + quad) ^ swz) * 8];
#pragma unroll
        for (int j = 0; j < 4; ++j) {
            f32x4 sa[4];
#pragma unroll
            for (int i = 0; i < 4; ++i) sa[i] = (f32x4){0.f, 0.f, 0.f, 0.f};
#pragma unroll
            for (int s = 0; s < 2; ++s)
#pragma unroll
                for (int i = 0; i < 4; ++i)
                    sa[i] = __builtin_amdgcn_mfma_f32_16x16x32_bf16(av[s][i], bB[s][j], sa[i], 0, 0, 0);
            const int f = f0 + j * 16 + col;
#pragma unroll
            for (int i = 0; i < 4; ++i) {
                const int tb = i * 16 + quad * 4;
                Qp[(tb + 0) * 264 + f] = f2bf(__expf(sa[i][0]) + 1e-6f);
                Qp[(tb + 1) * 264 + f] = f2bf(__expf(sa[i][1]) + 1e-6f);
                Qp[(tb + 2) * 264 + f] = f2bf(__expf(sa[i][2]) + 1e-6f);
                Qp[(tb + 3) * 264 + f] = f2bf(__expf(sa[i][3]) + 1e-6f);
            }
        }
        float dp = 0.f;
#pragma unroll
        for (int u = 0; u < 64; u += 8) {
            bf16x8 qv = *(const bf16x8*)&Qp[lane * 264 + f0 + u];
#pragma unroll
            for (int k2 = 0; k2 < 8; ++k2)
                dp += bf2f((unsigned short)qv[k2]) * KsS[f0 + u + k2];
        }
        denp[w][lane] = dp;
        __syncthreads();
        f32x4 nacc[4];
#pragma unroll
        for (int jn = 0; jn < 4; ++jn) nacc[jn] = (f32x4){0.f, 0.f, 0.f, 0.f};
#pragma unroll
        for (int s = 0; s < 8; ++s) {
            const int kc = s * 32 + quad * 8;
            bf16x8 aq = *(const bf16x8*)&Qp[(w * 16 + col) * 264 + kc];
#pragma unroll
            for (int jn = 0; jn < 4; ++jn) {
                bf16x8 bk = *(const bf16x8*)&KVTs[(jn * 16 + col) * 264 + kc];
                nacc[jn] = __builtin_amdgcn_mfma_f32_16x16x32_bf16(aq, bk, nacc[jn], 0, 0, 0);
            }
        }
#pragma unroll
        for (int r = 0; r < 4; ++r) {
            const int tl = w * 16 + quad * 4 + r;
            float den = denp[0][tl] + denp[1][tl] + denp[2][tl] + denp[3][tl];
            float rd = 1.f / fmaxf(den, 1e-6f);
            const size_t ob = (size_t)(b * kT + tg0 + tl) * kE + h * kD;
#pragma unroll
            for (int jn = 0; jn < 4; ++jn)
                attnb[ob + jn * 16 + col] = f2bf(nacc[jn][r] * rd);
        }
    }
}

// ---------------------------------------------------------------- launch
extern "C" void kernel_launch(void* const* d_in, const int* in_sizes, int n_in,
                              void* d_out, int out_size, void* d_ws, size_t ws_size,
                              hipStream_t stream) {
    (void)in_sizes; (void)n_in; (void)out_size; (void)ws_size;
    const float* x    = (const float*)d_in[0];
    const float* Wq   = (const float*)d_in[1];
    const float* Wk   = (const float*)d_in[2];
    const float* Wv   = (const float*)d_in[3];
    const float* Wo   = (const float*)d_in[4];
    const float* proj = (const float*)d_in[5];
    float* out = (float*)d_out;

    static int attr_done = 0;
    if (!attr_done) {
        hipFuncSetAttribute((const void*)gemm256_b16,
                            hipFuncAttributeMaxDynamicSharedMemorySize, 131072);
        hipFuncSetAttribute((const void*)gemm256_out,
                            hipFuncAttributeMaxDynamicSharedMemorySize, 131072);
        attr_done = 1;
    }

    char* ws = (char*)d_ws;
    unsigned short* QKVb  = (unsigned short*)(ws);               // 96MB
    unsigned short* attnb = (unsigned short*)(ws + 100663296);   // 32MB
    unsigned short* Abuf  = (unsigned short*)(ws + 100663296);   // aliases attnb (pre-gemm1)
    unsigned short* Btqkv = (unsigned short*)(ws + 134217728);   // 3MB
    unsigned short* WoT   = (unsigned short*)(ws + 137363456);   // 2MB
    unsigned short* projb = (unsigned short*)(ws + 139460608);   // 32KB
    float*          KVg   = (float*)(ws + 139493376);            // 4MB
    float*          Ksumg = (float*)(ws + 143687680);            // 64KB
    unsigned short* KVTb  = (unsigned short*)(ws + 143753216);   // 2MB

    copy_x_kernel<<<dim3(8192), 256, 0, stream>>>(x, out);

    trans_f2b_kernel<<<dim3(64, 8, 4), 256, 0, stream>>>(x, Abuf, kIn, kT,
                                                         (long)kIn * kT, (long)kT * kIn);
    trans_qkv_kernel<<<dim3(16, 8, 3), 256, 0, stream>>>(Wq, Wk, Wv, Btqkv);
    trans_f2b_kernel<<<dim3(16, 16, 1), 256, 0, stream>>>(Wo, WoT, kE, kE, 0, 0);
    f2b_flat_kernel<<<dim3(16), 256, 0, stream>>>(proj, projb, kF * kD / 4);

    // GEMM1: M=16384 x N=3072, K=512 -> 64 x 12 = 768 tiles
    gemm256_b16<<<dim3(768), 512, 131072, stream>>>(Abuf, Btqkv, QKVb, kQKVs, kIn, 12);

    const int nz = kB * kH * kF * kD + kB * kH * kF;
    zero_kernel<<<dim3((nz + 255) / 256), 256, 0, stream>>>(KVg, nz);

    phaseA_mfma<<<dim3(64, 8), 256, 0, stream>>>(QKVb, projb, KVg, Ksumg);
    trans_f2b_kernel<<<dim3(1, 4, 64), 256, 0, stream>>>(KVg, KVTb, kF, kD,
                                                         (long)kF * kD, (long)kF * kD);
    phaseB_mfma<<<dim3(64, 8), 256, 0, stream>>>(QKVb, projb, KVTb, Ksumg, attnb);

    // GEMM2: M=16384 x N=1024, K=1024 -> 64 x 4 = 256 tiles
    gemm256_out<<<dim3(256), 512, 131072, stream>>>(attnb, WoT, out, kE, kE, 4);
}

// Round 2
// 366.532 us; speedup vs baseline: 1.0198x; 1.0144x over previous
//
#include <hip/hip_runtime.h>

// PerformerAttnBlock — Round 6: GEMM K-tile restructured for fragment reuse.
// 24 ds_read_b128 per wave per K-tile (was 48): bv held in registers across
// both M-half phases; intra-tile barriers removed (2 barriers/tile, buffer
// lifetime only). Counted vmcnt(8) pipeline + T1/T2/T5 unchanged.
// B=4, IN=512, T=4096, EMBED=1024, H=16, D=64, F=256.
// WS (bytes):
//   0         QKVb bf16 [16384][3072] (96MB)
//   100663296 attnb bf16 [16384][1024] (32MB)  -- Abuf bf16 [16384][512] aliases pre-gemm1
//   134217728 Btqkv bf16 [3072][512] (3MB)
//   137363456 WoT bf16 [1024][1024] (2MB)
//   139460608 projb bf16 [256][64] (32KB)
//   139493376 KVg fp32 [64][256][64] (4MB)
//   143687680 Ksumg fp32 [64][256] (64KB)
//   143753216 KVTb bf16 [64][64][256] (2MB)

constexpr int kB  = 4;
constexpr int kIn = 512;
constexpr int kT  = 4096;
constexpr int kE  = 1024;
constexpr int kH  = 16;
constexpr int kD  = 64;
constexpr int kF  = 256;
constexpr int kQKVs = 3072;

typedef __attribute__((ext_vector_type(8))) short bf16x8;
typedef __attribute__((ext_vector_type(4))) float f32x4;

__device__ __forceinline__ unsigned short f2bf(float f) {
    unsigned u = __float_as_uint(f);
    u += 0x7fff + ((u >> 16) & 1);          // RNE
    return (unsigned short)(u >> 16);
}
__device__ __forceinline__ float bf2f(unsigned short s) {
    return __uint_as_float(((unsigned)s) << 16);
}
__device__ __forceinline__ void gload_lds16(const void* g, void* l) {
    __builtin_amdgcn_global_load_lds((const __attribute__((address_space(1))) void*)g,
                                     (__attribute__((address_space(3))) void*)l, 16, 0, 0);
}

// ---------------------------------------------------------------- zero
__global__ __launch_bounds__(256) void zero_kernel(float* __restrict__ p, int n) {
    int i = blockIdx.x * 256 + threadIdx.x;
    if (i < n) p[i] = 0.f;
}

// ---------------------------------------------------------------- copy x -> out[:, :512, :]
__global__ __launch_bounds__(256) void copy_x_kernel(const float* __restrict__ x,
                                                     float* __restrict__ out) {
    const int perB4 = kIn * kT / 4;
    int idx = blockIdx.x * 256 + threadIdx.x;
    if (idx < kB * perB4) {
        int b = idx / perB4, e = idx % perB4;
        ((float4*)out)[(size_t)b * ((kIn + kE) * kT / 4) + e] = ((const float4*)x)[idx];
    }
}

// ---------------------------------------------------------------- flat fp32->bf16
__global__ __launch_bounds__(256) void f2b_flat_kernel(const float* __restrict__ s,
                                                       unsigned short* __restrict__ d, int n4) {
    int i = blockIdx.x * 256 + threadIdx.x;
    if (i < n4) {
        float4 v = ((const float4*)s)[i];
        ushort4 o;
        o.x = f2bf(v.x); o.y = f2bf(v.y); o.z = f2bf(v.z); o.w = f2bf(v.w);
        ((ushort4*)d)[i] = o;
    }
}

// ---------------------------------------------------------------- transpose + fp32->bf16
// src [R][C] fp32 (+z*sstride), dst [C][R] bf16 (+z*dstride)
__global__ __launch_bounds__(256) void trans_f2b_kernel(const float* __restrict__ src,
                                                        unsigned short* __restrict__ dst,
                                                        int R, int C,
                                                        long sstride, long dstride) {
    __shared__ float L[64][68];
    src += (size_t)blockIdx.z * sstride;
    dst += (size_t)blockIdx.z * dstride;
    const int c0 = blockIdx.x * 64, r0 = blockIdx.y * 64;
    const int tid = threadIdx.x;
#pragma unroll
    for (int it = 0; it < 4; ++it) {
        int lin = it * 256 + tid;
        int i = lin >> 4;
        int j4 = (lin & 15) * 4;
        float4 v = *(const float4*)(src + (size_t)(r0 + i) * C + c0 + j4);
        L[j4 + 0][i] = v.x; L[j4 + 1][i] = v.y; L[j4 + 2][i] = v.z; L[j4 + 3][i] = v.w;
    }
    __syncthreads();
#pragma unroll
    for (int it = 0; it < 4; ++it) {
        int lin = it * 256 + tid;
        int cc = lin >> 4;
        int r4 = (lin & 15) * 4;
        ushort4 o;
        o.x = f2bf(L[cc][r4 + 0]); o.y = f2bf(L[cc][r4 + 1]);
        o.z = f2bf(L[cc][r4 + 2]); o.w = f2bf(L[cc][r4 + 3]);
        *(ushort4*)(dst + (size_t)(c0 + cc) * R + r0 + r4) = o;
    }
}

// ---------------------------------------------------------------- fused Wq/Wk/Wv transpose
__global__ __launch_bounds__(256) void trans_qkv_kernel(const float* __restrict__ Wq,
                                                        const float* __restrict__ Wk,
                                                        const float* __restrict__ Wv,
                                                        unsigned short* __restrict__ dst) {
    __shared__ float L[64][68];
    const int z = blockIdx.z;
    const float* src = (z == 0) ? Wq : (z == 1) ? Wk : Wv;
    dst += (size_t)z * kE * kIn;
    const int c0 = blockIdx.x * 64, r0 = blockIdx.y * 64;   // c over E, r over In
    const int tid = threadIdx.x;
#pragma unroll
    for (int it = 0; it < 4; ++it) {
        int lin = it * 256 + tid;
        int i = lin >> 4;
        int j4 = (lin & 15) * 4;
        float4 v = *(const float4*)(src + (size_t)(r0 + i) * kE + c0 + j4);
        L[j4 + 0][i] = v.x; L[j4 + 1][i] = v.y; L[j4 + 2][i] = v.z; L[j4 + 3][i] = v.w;
    }
    __syncthreads();
#pragma unroll
    for (int it = 0; it < 4; ++it) {
        int lin = it * 256 + tid;
        int cc = lin >> 4;
        int r4 = (lin & 15) * 4;
        ushort4 o;
        o.x = f2bf(L[cc][r4 + 0]); o.y = f2bf(L[cc][r4 + 1]);
        o.z = f2bf(L[cc][r4 + 2]); o.w = f2bf(L[cc][r4 + 3]);
        *(ushort4*)(dst + (size_t)(c0 + cc) * kIn + r0 + r4) = o;
    }
}

// ================================================================ 256x256 pipelined GEMM core
// 512 threads = 8 waves (2M x 4N); per-wave output 128x64 (acc[8][4] f32x4).
// LDS: 2 x (A[256][64] + B[256][64]) bf16 = 128KB, XOR chunk-swizzled.
// Per K-tile: 8 bv reads (held in regs) + 2 x 8 av reads + 64 MFMA = 24 ds_read_b128.
// Pipeline: tile t+2 staged after buf[t&1] freed; boundary wait = vmcnt(8).
__device__ __forceinline__ void stage256(const unsigned short* __restrict__ A,
                                         const unsigned short* __restrict__ Bt,
                                         int K, int m0, int n0, int kt,
                                         unsigned short* AsB, unsigned short* BsB,
                                         int tid) {
    const int w = tid >> 6;
    const size_t k0 = (size_t)kt * 64;
#pragma unroll
    for (int r = 0; r < 4; ++r) {
        int idx = r * 512 + tid;
        int row = idx >> 3;
        int cg = (idx & 7) ^ (row & 7);                  // pre-swizzled global source chunk
        gload_lds16(A + (size_t)(m0 + row) * K + k0 + cg * 8, AsB + r * 4096 + w * 512);
    }
#pragma unroll
    for (int r = 0; r < 4; ++r) {
        int idx = r * 512 + tid;
        int row = idx >> 3;
        int cg = (idx & 7) ^ (row & 7);
        gload_lds16(Bt + (size_t)(n0 + row) * K + k0 + cg * 8, BsB + r * 4096 + w * 512);
    }
}

__device__ __forceinline__ void gemm256_mainloop(const unsigned short* __restrict__ A,
                                                 const unsigned short* __restrict__ Bt,
                                                 int K, int m0, int n0,
                                                 unsigned short* smem,
                                                 f32x4 (&acc)[8][4]) {
    const int tid = threadIdx.x, lane = tid & 63, w = tid >> 6;
    const int col = lane & 15, quad = lane >> 4;
    const int wm = (w >> 2) * 128, wn = (w & 3) * 64;
    const int swz = col & 7;
    const int nt = K >> 6;
    unsigned short* As0 = smem;
    unsigned short* As1 = smem + 16384;
    unsigned short* Bs0 = smem + 32768;
    unsigned short* Bs1 = smem + 49152;

    stage256(A, Bt, K, m0, n0, 0, As0, Bs0, tid);
    stage256(A, Bt, K, m0, n0, 1, As1, Bs1, tid);
#pragma unroll
    for (int i = 0; i < 8; ++i)
#pragma unroll
        for (int j = 0; j < 4; ++j) acc[i][j] = (f32x4){0.f, 0.f, 0.f, 0.f};
    asm volatile("s_waitcnt vmcnt(8)" ::: "memory");     // tile 0 landed; tile 1 in flight
    __builtin_amdgcn_s_barrier();
    __builtin_amdgcn_sched_barrier(0);

    for (int t = 0; ; ++t) {
        const unsigned short* As_ = (t & 1) ? As1 : As0;
        const unsigned short* Bs_ = (t & 1) ? Bs1 : Bs0;
        // B fragments once per tile, held in registers across both M-halves
        bf16x8 bv[2][4];
#pragma unroll
        for (int s = 0; s < 2; ++s) {
            const int kc = ((s * 4 + quad) ^ swz) * 8;
#pragma unroll
            for (int j = 0; j < 4; ++j)
                bv[s][j] = *(const bf16x8*)&Bs_[(wn + j * 16 + col) * 64 + kc];
        }
        // phase A: M-rows wm..wm+63
        {
            bf16x8 av[2][4];
#pragma unroll
            for (int s = 0; s < 2; ++s) {
                const int kc = ((s * 4 + quad) ^ swz) * 8;
#pragma unroll
                for (int i = 0; i < 4; ++i)
                    av[s][i] = *(const bf16x8*)&As_[(wm + i * 16 + col) * 64 + kc];
            }
            __builtin_amdgcn_s_setprio(1);
#pragma unroll
            for (int s = 0; s < 2; ++s)
#pragma unroll
                for (int i = 0; i < 4; ++i)
#pragma unroll
                    for (int j = 0; j < 4; ++j)
                        acc[i][j] = __builtin_amdgcn_mfma_f32_16x16x32_bf16(
                            av[s][i], bv[s][j], acc[i][j], 0, 0, 0);
            __builtin_amdgcn_s_setprio(0);
        }
        // phase B: M-rows wm+64..wm+127, reuse bv
        {
            bf16x8 av[2][4];
#pragma unroll
            for (int s = 0; s < 2; ++s) {
                const int kc = ((s * 4 + quad) ^ swz) * 8;
#pragma unroll
                for (int i = 0; i < 4; ++i)
                    av[s][i] = *(const bf16x8*)&As_[(wm + 64 + i * 16 + col) * 64 + kc];
            }
            __builtin_amdgcn_s_setprio(1);
#pragma unroll
            for (int s = 0; s < 2; ++s)
#pragma unroll
                for (int i = 0; i < 4; ++i)
#pragma unroll
                    for (int j = 0; j < 4; ++j)
                        acc[4 + i][j] = __builtin_amdgcn_mfma_f32_16x16x32_bf16(
                            av[s][i], bv[s][j], acc[4 + i][j], 0, 0, 0);
            __builtin_amdgcn_s_setprio(0);
        }
        __builtin_amdgcn_sched_barrier(0);
        __builtin_amdgcn_s_barrier();        // all waves done reading buf[t&1]
        __builtin_amdgcn_sched_barrier(0);
        if (t == nt - 1) break;
        if (t + 2 < nt) {
            stage256(A, Bt, K, m0, n0, t + 2, (t & 1) ? As1 : As0, (t & 1) ? Bs1 : Bs0, tid);
            asm volatile("s_waitcnt vmcnt(8)" ::: "memory");   // tile t+1 landed
        } else {
            asm volatile("s_waitcnt vmcnt(0)" ::: "memory");   // drain last tile
        }
        __builtin_amdgcn_sched_barrier(0);
        __builtin_amdgcn_s_barrier();        // buf[t+1] visible to all
        __builtin_amdgcn_sched_barrier(0);
    }
}

// ---------------------------------------------------------------- GEMM1: bf16 out
__global__ __launch_bounds__(512) void gemm256_b16(const unsigned short* __restrict__ A,
                                                   const unsigned short* __restrict__ Bt,
                                                   unsigned short* __restrict__ C,
                                                   int N, int K, int ntN) {
    extern __shared__ unsigned short smem_us[];
    const int tid = threadIdx.x, lane = tid & 63, w = tid >> 6;
    const int col = lane & 15, quad = lane >> 4;
    const int wm = (w >> 2) * 128, wn = (w & 3) * 64;
    // XCD-chunked bijective swizzle (gridDim.x % 8 == 0)
    const int bid = blockIdx.x;
    const int qch = gridDim.x >> 3;
    const int swb = (bid & 7) * qch + (bid >> 3);
    const int mt = swb / ntN, ntl = swb - mt * ntN;
    const int m0 = mt * 256, n0 = ntl * 256;

    f32x4 acc[8][4];
    gemm256_mainloop(A, Bt, K, m0, n0, smem_us, acc);

    // epilogue: per-wave LDS repack (reuses smem; all waves past final barrier)
    float* Tw = (float*)smem_us + w * 336;
    const int t2 = lane >> 2, n4 = (lane & 3) * 4;
#pragma unroll
    for (int ri = 0; ri < 8; ++ri)
#pragma unroll
        for (int cj = 0; cj < 4; ++cj) {
#pragma unroll
            for (int r = 0; r < 4; ++r)
                Tw[(quad * 4 + r) * 20 + col] = acc[ri][cj][r];
            float4 v = *(const float4*)&Tw[t2 * 20 + n4];
            ushort4 o;
            o.x = f2bf(v.x); o.y = f2bf(v.y); o.z = f2bf(v.z); o.w = f2bf(v.w);
            *(ushort4*)(C + (size_t)(m0 + wm + ri * 16 + t2) * N + n0 + wn + cj * 16 + n4) = o;
        }
}

// ---------------------------------------------------------------- GEMM2: attn @ Wo, fp32 transposed out
__global__ __launch_bounds__(512) void gemm256_out(const unsigned short* __restrict__ A,
                                                   const unsigned short* __restrict__ Bt,
                                                   float* __restrict__ out,
                                                   int N, int K, int ntN) {
    extern __shared__ unsigned short smem_us[];
    const int tid = threadIdx.x, lane = tid & 63, w = tid >> 6;
    const int col = lane & 15, quad = lane >> 4;
    const int wm = (w >> 2) * 128, wn = (w & 3) * 64;
    const int bid = blockIdx.x;
    const int qch = gridDim.x >> 3;
    const int swb = (bid & 7) * qch + (bid >> 3);
    const int mt = swb / ntN, ntl = swb - mt * ntN;
    const int m0 = mt * 256, n0 = ntl * 256;

    f32x4 acc[8][4];
    gemm256_mainloop(A, Bt, K, m0, n0, smem_us, acc);

    // epilogue: transpose per 16x16 fragment in per-wave LDS, store out[n][t] coalesced
    const int b = m0 >> 12, t0 = m0 & 4095;
    float* dst = out + (size_t)b * (kIn + kE) * kT + (size_t)kIn * kT;
    float* Tw = (float*)smem_us + w * 336;
    const int n2 = lane >> 2, t4 = (lane & 3) * 4;
#pragma unroll
    for (int ri = 0; ri < 8; ++ri)
#pragma unroll
        for (int cj = 0; cj < 4; ++cj) {
            *(float4*)&Tw[col * 20 + quad * 4] =
                (float4){acc[ri][cj][0], acc[ri][cj][1], acc[ri][cj][2], acc[ri][cj][3]};
            float4 v = *(const float4*)&Tw[n2 * 20 + t4];
            *(float4*)(dst + (size_t)(n0 + wn + cj * 16 + n2) * kT + t0 + wm + ri * 16 + t4) = v;
        }
}

// ---------------------------------------------------------------- Phase A (MFMA): KV, Ksum
__global__ __launch_bounds__(256) void phaseA_mfma(const unsigned short* __restrict__ QKVb,
                                                   const unsigned short* __restrict__ projb,
                                                   float* __restrict__ KVg,
                                                   float* __restrict__ Ksumg) {
    __shared__ unsigned short Ks[64 * 64];     // [t][d] XOR-swizzled chunks
    __shared__ unsigned short VT[64 * 72];     // [d][t] pad 8
    __shared__ unsigned short KpT[256 * 72];   // [f][t] pad 8
    const int tid = threadIdx.x, lane = tid & 63, w = tid >> 6;
    const int col = lane & 15, quad = lane >> 4;
    const int bh = blockIdx.x, b = bh >> 4, h = bh & 15;
    const int grp = blockIdx.y;
    const int f0 = w * 64;
    const int swz = col & 7;

    bf16x8 bB[2][4];   // proj B-fragments, invariant
#pragma unroll
    for (int s = 0; s < 2; ++s)
#pragma unroll
        for (int j = 0; j < 4; ++j)
            bB[s][j] = *(const bf16x8*)(projb + (size_t)(f0 + j * 16 + col) * 64 + s * 32 + quad * 8);

    f32x4 kvacc[4][4];
#pragma unroll
    for (int i = 0; i < 4; ++i)
#pragma unroll
        for (int j = 0; j < 4; ++j) kvacc[i][j] = (f32x4){0.f, 0.f, 0.f, 0.f};
    float ksum_acc[4] = {0.f, 0.f, 0.f, 0.f};

    for (int it = 0; it < 8; ++it) {
        const size_t rowbase = (size_t)(b * kT + grp * 512 + it * 64) * kQKVs + h * kD;
        __syncthreads();
#pragma unroll
        for (int i2 = 0; i2 < 2; ++i2) {
            int p = (i2 * 4 + w) * 64 + lane;
            int row = p >> 3;
            int cg = ((p & 7) ^ (row & 7)) * 8;
            gload_lds16(QKVb + rowbase + 1024 + (size_t)row * kQKVs + cg, &Ks[(i2 * 4 + w) * 512]);
        }
#pragma unroll
        for (int r = 0; r < 4; ++r) {
            int lin = r * 256 + tid;
            int t = lin >> 4, d4 = (lin & 15) * 4;
            ushort4 v = *(const ushort4*)(QKVb + rowbase + 2048 + (size_t)t * kQKVs + d4);
            VT[(d4 + 0) * 72 + t] = v.x; VT[(d4 + 1) * 72 + t] = v.y;
            VT[(d4 + 2) * 72 + t] = v.z; VT[(d4 + 3) * 72 + t] = v.w;
        }
        __syncthreads();
        bf16x8 av[2][4];
#pragma unroll
        for (int s = 0; s < 2; ++s)
#pragma unroll
            for (int i = 0; i < 4; ++i)
                av[s][i] = *(const bf16x8*)&Ks[(i * 16 + col) * 64 + ((s * 4 + quad) ^ swz) * 8];
#pragma unroll
        for (int j = 0; j < 4; ++j) {
            f32x4 sa[4];
#pragma unroll
            for (int i = 0; i < 4; ++i) sa[i] = (f32x4){0.f, 0.f, 0.f, 0.f};
#pragma unroll
            for (int s = 0; s < 2; ++s)
#pragma unroll
                for (int i = 0; i < 4; ++i)
                    sa[i] = __builtin_amdgcn_mfma_f32_16x16x32_bf16(av[s][i], bB[s][j], sa[i], 0, 0, 0);
            const int f = f0 + j * 16 + col;
#pragma unroll
            for (int i = 0; i < 4; ++i) {
                float e0 = __expf(sa[i][0]) + 1e-6f;
                float e1 = __expf(sa[i][1]) + 1e-6f;
                float e2 = __expf(sa[i][2]) + 1e-6f;
                float e3 = __expf(sa[i][3]) + 1e-6f;
                ksum_acc[j] += (e0 + e1) + (e2 + e3);
                ushort4 pk;
                pk.x = f2bf(e0); pk.y = f2bf(e1); pk.z = f2bf(e2); pk.w = f2bf(e3);
                *(ushort4*)&KpT[f * 72 + i * 16 + quad * 4] = pk;
            }
        }
#pragma unroll
        for (int s = 0; s < 2; ++s) {
            const int kc = s * 32 + quad * 8;
            bf16x8 a2[4], b2[4];
#pragma unroll
            for (int i = 0; i < 4; ++i)
                a2[i] = *(const bf16x8*)&KpT[(f0 + i * 16 + col) * 72 + kc];
#pragma unroll
            for (int jn = 0; jn < 4; ++jn)
                b2[jn] = *(const bf16x8*)&VT[(jn * 16 + col) * 72 + kc];
#pragma unroll
            for (int i = 0; i < 4; ++i)
#pragma unroll
                for (int jn = 0; jn < 4; ++jn)
                    kvacc[i][jn] = __builtin_amdgcn_mfma_f32_16x16x32_bf16(a2[i], b2[jn], kvacc[i][jn], 0, 0, 0);
        }
    }
    const size_t kvbase = (size_t)bh * (kF * kD);
#pragma unroll
    for (int i = 0; i < 4; ++i)
#pragma unroll
        for (int jn = 0; jn < 4; ++jn)
#pragma unroll
            for (int r = 0; r < 4; ++r)
                atomicAdd(&KVg[kvbase + (size_t)(f0 + i * 16 + quad * 4 + r) * kD + jn * 16 + col],
                          kvacc[i][jn][r]);
#pragma unroll
    for (int j = 0; j < 4; ++j) {
        float v = ksum_acc[j];
        v += __shfl_xor(v, 16);
        v += __shfl_xor(v, 32);
        if (quad == 0) atomicAdd(&Ksumg[(size_t)bh * kF + f0 + j * 16 + col], v);
    }
}

// ---------------------------------------------------------------- Phase B (MFMA): attn bf16
__global__ __launch_bounds__(256) void phaseB_mfma(const unsigned short* __restrict__ QKVb,
                                                   const unsigned short* __restrict__ projb,
                                                   const unsigned short* __restrict__ KVTb,
                                                   const float* __restrict__ Ksumg,
                                                   unsigned short* __restrict__ attnb) {
    __shared__ unsigned short Qs[64 * 64];      // [t][d] XOR-swizzled chunks
    __shared__ unsigned short Qp[64 * 264];     // [t][f] pad 8
    __shared__ unsigned short KVTs[64 * 264];   // [d][f] pad 8
    __shared__ float KsS[256];
    __shared__ float denp[4][64];
    const int tid = threadIdx.x, lane = tid & 63, w = tid >> 6;
    const int col = lane & 15, quad = lane >> 4;
    const int bh = blockIdx.x, b = bh >> 4, h = bh & 15;
    const int grp = blockIdx.y;
    const int f0 = w * 64;
    const int swz = col & 7;

    bf16x8 bB[2][4];
#pragma unroll
    for (int s = 0; s < 2; ++s)
#pragma unroll
        for (int j = 0; j < 4; ++j)
            bB[s][j] = *(const bf16x8*)(projb + (size_t)(f0 + j * 16 + col) * 64 + s * 32 + quad * 8);

#pragma unroll
    for (int r = 0; r < 8; ++r) {
        int lin = r * 256 + tid;
        int d = lin >> 5, fc8 = (lin & 31) * 8;
        *(bf16x8*)&KVTs[d * 264 + fc8] = *(const bf16x8*)(KVTb + (size_t)bh * 16384 + d * 256 + fc8);
    }
    KsS[tid] = Ksumg[(size_t)bh * kF + tid];

    for (int it = 0; it < 8; ++it) {
        const int tg0 = grp * 512 + it * 64;
        const size_t rowbase = (size_t)(b * kT + tg0) * kQKVs + h * kD;
        __syncthreads();
#pragma unroll
        for (int i2 = 0; i2 < 2; ++i2) {
            int p = (i2 * 4 + w) * 64 + lane;
            int row = p >> 3;
            int cg = ((p & 7) ^ (row & 7)) * 8;
            gload_lds16(QKVb + rowbase + (size_t)row * kQKVs + cg, &Qs[(i2 * 4 + w) * 512]);
        }
        __syncthreads();
        bf16x8 av[2][4];
#pragma unroll
        for (int s = 0; s < 2; ++s)
#pragma unroll
            for (int i = 0; i < 4; ++i)
                av[s][i] = *(const bf16x8*)&Qs[(i * 16 + col) * 64 + ((s * 4 + quad) ^ swz) * 8];
#pragma unroll
        for (int j = 0; j < 4; ++j) {
            f32x4 sa[4];
#pragma unroll
            for (int i = 0; i < 4; ++i) sa[i] = (f32x4){0.f, 0.f, 0.f, 0.f};
#pragma unroll
            for (int s = 0; s < 2; ++s)
#pragma unroll
                for (int i = 0; i < 4; ++i)
                    sa[i] = __builtin_amdgcn_mfma_f32_16x16x32_bf16(av[s][i], bB[s][j], sa[i], 0, 0, 0);
            const int f = f0 + j * 16 + col;
#pragma unroll
            for (int i = 0; i < 4; ++i) {
                const int tb = i * 16 + quad * 4;
                Qp[(tb + 0) * 264 + f] = f2bf(__expf(sa[i][0]) + 1e-6f);
                Qp[(tb + 1) * 264 + f] = f2bf(__expf(sa[i][1]) + 1e-6f);
                Qp[(tb + 2) * 264 + f] = f2bf(__expf(sa[i][2]) + 1e-6f);
                Qp[(tb + 3) * 264 + f] = f2bf(__expf(sa[i][3]) + 1e-6f);
            }
        }
        float dp = 0.f;
#pragma unroll
        for (int u = 0; u < 64; u += 8) {
            bf16x8 qv = *(const bf16x8*)&Qp[lane * 264 + f0 + u];
#pragma unroll
            for (int k2 = 0; k2 < 8; ++k2)
                dp += bf2f((unsigned short)qv[k2]) * KsS[f0 + u + k2];
        }
        denp[w][lane] = dp;
        __syncthreads();
        f32x4 nacc[4];
#pragma unroll
        for (int jn = 0; jn < 4; ++jn) nacc[jn] = (f32x4){0.f, 0.f, 0.f, 0.f};
#pragma unroll
        for (int s = 0; s < 8; ++s) {
            const int kc = s * 32 + quad * 8;
            bf16x8 aq = *(const bf16x8*)&Qp[(w * 16 + col) * 264 + kc];
#pragma unroll
            for (int jn = 0; jn < 4; ++jn) {
                bf16x8 bk = *(const bf16x8*)&KVTs[(jn * 16 + col) * 264 + kc];
                nacc[jn] = __builtin_amdgcn_mfma_f32_16x16x32_bf16(aq, bk, nacc[jn], 0, 0, 0);
            }
        }
#pragma unroll
        for (int r = 0; r < 4; ++r) {
            const int tl = w * 16 + quad * 4 + r;
            float den = denp[0][tl] + denp[1][tl] + denp[2][tl] + denp[3][tl];
            float rd = 1.f / fmaxf(den, 1e-6f);
            const size_t ob = (size_t)(b * kT + tg0 + tl) * kE + h * kD;
#pragma unroll
            for (int jn = 0; jn < 4; ++jn)
                attnb[ob + jn * 16 + col] = f2bf(nacc[jn][r] * rd);
        }
    }
}

// ---------------------------------------------------------------- launch
extern "C" void kernel_launch(void* const* d_in, const int* in_sizes, int n_in,
                              void* d_out, int out_size, void* d_ws, size_t ws_size,
                              hipStream_t stream) {
    (void)in_sizes; (void)n_in; (void)out_size; (void)ws_size;
    const float* x    = (const float*)d_in[0];
    const float* Wq   = (const float*)d_in[1];
    const float* Wk   = (const float*)d_in[2];
    const float* Wv   = (const float*)d_in[3];
    const float* Wo   = (const float*)d_in[4];
    const float* proj = (const float*)d_in[5];
    float* out = (float*)d_out;

    static int attr_done = 0;
    if (!attr_done) {
        hipFuncSetAttribute((const void*)gemm256_b16,
                            hipFuncAttributeMaxDynamicSharedMemorySize, 131072);
        hipFuncSetAttribute((const void*)gemm256_out,
                            hipFuncAttributeMaxDynamicSharedMemorySize, 131072);
        attr_done = 1;
    }

    char* ws = (char*)d_ws;
    unsigned short* QKVb  = (unsigned short*)(ws);               // 96MB
    unsigned short* attnb = (unsigned short*)(ws + 100663296);   // 32MB
    unsigned short* Abuf  = (unsigned short*)(ws + 100663296);   // aliases attnb (pre-gemm1)
    unsigned short* Btqkv = (unsigned short*)(ws + 134217728);   // 3MB
    unsigned short* WoT   = (unsigned short*)(ws + 137363456);   // 2MB
    unsigned short* projb = (unsigned short*)(ws + 139460608);   // 32KB
    float*          KVg   = (float*)(ws + 139493376);            // 4MB
    float*          Ksumg = (float*)(ws + 143687680);            // 64KB
    unsigned short* KVTb  = (unsigned short*)(ws + 143753216);   // 2MB

    copy_x_kernel<<<dim3(8192), 256, 0, stream>>>(x, out);

    trans_f2b_kernel<<<dim3(64, 8, 4), 256, 0, stream>>>(x, Abuf, kIn, kT,
                                                         (long)kIn * kT, (long)kT * kIn);
    trans_qkv_kernel<<<dim3(16, 8, 3), 256, 0, stream>>>(Wq, Wk, Wv, Btqkv);
    trans_f2b_kernel<<<dim3(16, 16, 1), 256, 0, stream>>>(Wo, WoT, kE, kE, 0, 0);
    f2b_flat_kernel<<<dim3(16), 256, 0, stream>>>(proj, projb, kF * kD / 4);

    // GEMM1: M=16384 x N=3072, K=512 -> 64 x 12 = 768 tiles
    gemm256_b16<<<dim3(768), 512, 131072, stream>>>(Abuf, Btqkv, QKVb, kQKVs, kIn, 12);

    const int nz = kB * kH * kF * kD + kB * kH * kF;
    zero_kernel<<<dim3((nz + 255) / 256), 256, 0, stream>>>(KVg, nz);

    phaseA_mfma<<<dim3(64, 8), 256, 0, stream>>>(QKVb, projb, KVg, Ksumg);
    trans_f2b_kernel<<<dim3(1, 4, 64), 256, 0, stream>>>(KVg, KVTb, kF, kD,
                                                         (long)kF * kD, (long)kF * kD);
    phaseB_mfma<<<dim3(64, 8), 256, 0, stream>>>(QKVb, projb, KVTb, Ksumg, attnb);

    // GEMM2: M=16384 x N=1024, K=1024 -> 64 x 4 = 256 tiles
    gemm256_out<<<dim3(256), 512, 131072, stream>>>(attnb, WoT, out, kE, kE, 4);
}

// Round 3
// 363.132 us; speedup vs baseline: 1.0294x; 1.0094x over previous
//
#include <hip/hip_runtime.h>

// PerformerAttnBlock — Round 7: true m201 8-phase schedule in gemm256 mainloop.
// Per 2-K-tile iteration: 8 phases x {ds_read subtile + 2 gload_lds stage ->
// barrier -> lgkmcnt(0) -> setprio(1) 16 MFMA setprio(0) -> barrier};
// counted vmcnt(6) only at phases 4/8. Fragment partitioning (bv reg-resident
// per K-tile, 24 ds_read/K-tile) kept from Round 6.
// B=4, IN=512, T=4096, EMBED=1024, H=16, D=64, F=256.
// WS (bytes):
//   0         QKVb bf16 [16384][3072] (96MB)
//   100663296 attnb bf16 [16384][1024] (32MB)  -- Abuf bf16 [16384][512] aliases pre-gemm1
//   134217728 Btqkv bf16 [3072][512] (3MB)
//   137363456 WoT bf16 [1024][1024] (2MB)
//   139460608 projb bf16 [256][64] (32KB)
//   139493376 KVg fp32 [64][256][64] (4MB)
//   143687680 Ksumg fp32 [64][256] (64KB)
//   143753216 KVTb bf16 [64][64][256] (2MB)

constexpr int kB  = 4;
constexpr int kIn = 512;
constexpr int kT  = 4096;
constexpr int kE  = 1024;
constexpr int kH  = 16;
constexpr int kD  = 64;
constexpr int kF  = 256;
constexpr int kQKVs = 3072;

typedef __attribute__((ext_vector_type(8))) short bf16x8;
typedef __attribute__((ext_vector_type(4))) float f32x4;

__device__ __forceinline__ unsigned short f2bf(float f) {
    unsigned u = __float_as_uint(f);
    u += 0x7fff + ((u >> 16) & 1);          // RNE
    return (unsigned short)(u >> 16);
}
__device__ __forceinline__ float bf2f(unsigned short s) {
    return __uint_as_float(((unsigned)s) << 16);
}
__device__ __forceinline__ void gload_lds16(const void* g, void* l) {
    __builtin_amdgcn_global_load_lds((const __attribute__((address_space(1))) void*)g,
                                     (__attribute__((address_space(3))) void*)l, 16, 0, 0);
}

// ---------------------------------------------------------------- zero
__global__ __launch_bounds__(256) void zero_kernel(float* __restrict__ p, int n) {
    int i = blockIdx.x * 256 + threadIdx.x;
    if (i < n) p[i] = 0.f;
}

// ---------------------------------------------------------------- copy x -> out[:, :512, :]
__global__ __launch_bounds__(256) void copy_x_kernel(const float* __restrict__ x,
                                                     float* __restrict__ out) {
    const int perB4 = kIn * kT / 4;
    int idx = blockIdx.x * 256 + threadIdx.x;
    if (idx < kB * perB4) {
        int b = idx / perB4, e = idx % perB4;
        ((float4*)out)[(size_t)b * ((kIn + kE) * kT / 4) + e] = ((const float4*)x)[idx];
    }
}

// ---------------------------------------------------------------- flat fp32->bf16
__global__ __launch_bounds__(256) void f2b_flat_kernel(const float* __restrict__ s,
                                                       unsigned short* __restrict__ d, int n4) {
    int i = blockIdx.x * 256 + threadIdx.x;
    if (i < n4) {
        float4 v = ((const float4*)s)[i];
        ushort4 o;
        o.x = f2bf(v.x); o.y = f2bf(v.y); o.z = f2bf(v.z); o.w = f2bf(v.w);
        ((ushort4*)d)[i] = o;
    }
}

// ---------------------------------------------------------------- transpose + fp32->bf16
// src [R][C] fp32 (+z*sstride), dst [C][R] bf16 (+z*dstride)
__global__ __launch_bounds__(256) void trans_f2b_kernel(const float* __restrict__ src,
                                                        unsigned short* __restrict__ dst,
                                                        int R, int C,
                                                        long sstride, long dstride) {
    __shared__ float L[64][68];
    src += (size_t)blockIdx.z * sstride;
    dst += (size_t)blockIdx.z * dstride;
    const int c0 = blockIdx.x * 64, r0 = blockIdx.y * 64;
    const int tid = threadIdx.x;
#pragma unroll
    for (int it = 0; it < 4; ++it) {
        int lin = it * 256 + tid;
        int i = lin >> 4;
        int j4 = (lin & 15) * 4;
        float4 v = *(const float4*)(src + (size_t)(r0 + i) * C + c0 + j4);
        L[j4 + 0][i] = v.x; L[j4 + 1][i] = v.y; L[j4 + 2][i] = v.z; L[j4 + 3][i] = v.w;
    }
    __syncthreads();
#pragma unroll
    for (int it = 0; it < 4; ++it) {
        int lin = it * 256 + tid;
        int cc = lin >> 4;
        int r4 = (lin & 15) * 4;
        ushort4 o;
        o.x = f2bf(L[cc][r4 + 0]); o.y = f2bf(L[cc][r4 + 1]);
        o.z = f2bf(L[cc][r4 + 2]); o.w = f2bf(L[cc][r4 + 3]);
        *(ushort4*)(dst + (size_t)(c0 + cc) * R + r0 + r4) = o;
    }
}

// ---------------------------------------------------------------- fused Wq/Wk/Wv transpose
__global__ __launch_bounds__(256) void trans_qkv_kernel(const float* __restrict__ Wq,
                                                        const float* __restrict__ Wk,
                                                        const float* __restrict__ Wv,
                                                        unsigned short* __restrict__ dst) {
    __shared__ float L[64][68];
    const int z = blockIdx.z;
    const float* src = (z == 0) ? Wq : (z == 1) ? Wk : Wv;
    dst += (size_t)z * kE * kIn;
    const int c0 = blockIdx.x * 64, r0 = blockIdx.y * 64;   // c over E, r over In
    const int tid = threadIdx.x;
#pragma unroll
    for (int it = 0; it < 4; ++it) {
        int lin = it * 256 + tid;
        int i = lin >> 4;
        int j4 = (lin & 15) * 4;
        float4 v = *(const float4*)(src + (size_t)(r0 + i) * kE + c0 + j4);
        L[j4 + 0][i] = v.x; L[j4 + 1][i] = v.y; L[j4 + 2][i] = v.z; L[j4 + 3][i] = v.w;
    }
    __syncthreads();
#pragma unroll
    for (int it = 0; it < 4; ++it) {
        int lin = it * 256 + tid;
        int cc = lin >> 4;
        int r4 = (lin & 15) * 4;
        ushort4 o;
        o.x = f2bf(L[cc][r4 + 0]); o.y = f2bf(L[cc][r4 + 1]);
        o.z = f2bf(L[cc][r4 + 2]); o.w = f2bf(L[cc][r4 + 3]);
        *(ushort4*)(dst + (size_t)(c0 + cc) * kIn + r0 + r4) = o;
    }
}

// ================================================================ 256x256 8-phase GEMM core
// 512 threads = 8 waves (2M x 4N); per-wave output 128x64 (acc[8][4] f32x4).
// LDS: P/Q dbuf x (A[256][64] + B[256][64]) bf16 = 128KB, XOR chunk-swizzled.
// Iteration i computes K-tiles 2i (P) and 2i+1 (Q) in 8 phases; each phase
// issues 2 stage units (gload_lds 8KB) of tiles 2i+2/2i+3 into freed regions.
// vmcnt(6) only at phase 4 (Q ready) and phase 8 (next P ready).
__device__ __forceinline__ void gemm256_mainloop(const unsigned short* __restrict__ A,
                                                 const unsigned short* __restrict__ Bt,
                                                 int K, int m0, int n0,
                                                 unsigned short* smem,
                                                 f32x4 (&acc)[8][4]) {
    const int tid = threadIdx.x, lane = tid & 63, w = tid >> 6;
    const int col = lane & 15, quad = lane >> 4;
    const int wm = (w >> 2) * 128, wn = (w & 3) * 64;
    const int swz = col & 7;
    const int nt = K >> 6;          // even, >= 4
    const int L = (nt >> 1) - 1;

    unsigned short* PA = smem;
    unsigned short* QA = smem + 16384;
    unsigned short* PB = smem + 32768;
    unsigned short* QB = smem + 49152;

    // staging address precompute: unit r covers rows r*64..r*64+63; chunk xor const
    const int rowb = tid >> 3;
    const int cgc = ((tid & 7) ^ (rowb & 7)) * 8;
    const unsigned short* Ag = A + (size_t)(m0 + rowb) * K + cgc;
    const unsigned short* Bg = Bt + (size_t)(n0 + rowb) * K + cgc;
    unsigned short* PAw = PA + w * 512;
    unsigned short* QAw = QA + w * 512;
    unsigned short* PBw = PB + w * 512;
    unsigned short* QBw = QB + w * 512;

    auto stage = [&](const unsigned short* g, int kt, int r, unsigned short* lw) {
        gload_lds16(g + (size_t)kt * 64 + (size_t)(r * 64) * K, lw + r * 4096);
    };
    auto sync_open = [&]() {
        __builtin_amdgcn_sched_barrier(0);
        __builtin_amdgcn_s_barrier();
        asm volatile("s_waitcnt lgkmcnt(0)" ::: "memory");
        __builtin_amdgcn_sched_barrier(0);
    };
    auto sync_close = [&]() {
        __builtin_amdgcn_sched_barrier(0);
        __builtin_amdgcn_s_barrier();
        __builtin_amdgcn_sched_barrier(0);
    };

    bf16x8 bv[2][4], av[4];
    auto load_bv = [&](const unsigned short* Bbuf) {
#pragma unroll
        for (int s = 0; s < 2; ++s) {
            const int kc = ((s * 4 + quad) ^ swz) * 8;
#pragma unroll
            for (int j = 0; j < 4; ++j)
                bv[s][j] = *(const bf16x8*)&Bbuf[(wn + j * 16 + col) * 64 + kc];
        }
    };
    auto load_av = [&](const unsigned short* Abuf, int mh, int s) {
        const int kc = ((s * 4 + quad) ^ swz) * 8;
#pragma unroll
        for (int i4 = 0; i4 < 4; ++i4)
            av[i4] = *(const bf16x8*)&Abuf[(wm + mh * 64 + i4 * 16 + col) * 64 + kc];
    };
    auto mfma_lo = [&](const bf16x8* bvr) {
        __builtin_amdgcn_s_setprio(1);
#pragma unroll
        for (int i4 = 0; i4 < 4; ++i4)
#pragma unroll
            for (int j = 0; j < 4; ++j)
                acc[i4][j] = __builtin_amdgcn_mfma_f32_16x16x32_bf16(av[i4], bvr[j], acc[i4][j], 0, 0, 0);
        __builtin_amdgcn_s_setprio(0);
    };
    auto mfma_hi = [&](const bf16x8* bvr) {
        __builtin_amdgcn_s_setprio(1);
#pragma unroll
        for (int i4 = 0; i4 < 4; ++i4)
#pragma unroll
            for (int j = 0; j < 4; ++j)
                acc[4 + i4][j] = __builtin_amdgcn_mfma_f32_16x16x32_bf16(av[i4], bvr[j], acc[4 + i4][j], 0, 0, 0);
        __builtin_amdgcn_s_setprio(0);
    };

    // prologue: tile0 -> P (full, 8 units), tile1 -> Q (B full + A{0,2}, 6 units)
#pragma unroll
    for (int r = 0; r < 4; ++r) stage(Bg, 0, r, PBw);
#pragma unroll
    for (int r = 0; r < 4; ++r) stage(Ag, 0, r, PAw);
#pragma unroll
    for (int r = 0; r < 4; ++r) stage(Bg, 1, r, QBw);
    stage(Ag, 1, 0, QAw);
    stage(Ag, 1, 2, QAw);
#pragma unroll
    for (int i = 0; i < 8; ++i)
#pragma unroll
        for (int j = 0; j < 4; ++j) acc[i][j] = (f32x4){0.f, 0.f, 0.f, 0.f};
    asm volatile("s_waitcnt vmcnt(6)" ::: "memory");   // tile0 landed; Q's 6 in flight
    __builtin_amdgcn_s_barrier();
    __builtin_amdgcn_sched_barrier(0);

    for (int t = 0; t <= L; ++t) {
        const bool more = (t < L);
        const int ktA = 2 * t + 2, ktB = 2 * t + 3;
        // ---- Phase 1: P m0 s0; bv <- P.B (both slices); stage A(2t+1){1,3} -> Q.A
        load_bv(PB);
        load_av(PA, 0, 0);
        stage(Ag, 2 * t + 1, 1, QAw);
        stage(Ag, 2 * t + 1, 3, QAw);
        sync_open(); mfma_lo(bv[0]); sync_close();
        // ---- Phase 2: P m0 s1; stage B(ktA){0,1} -> P.B (P.B freed at Ph1)
        load_av(PA, 0, 1);
        if (more) { stage(Bg, ktA, 0, PBw); stage(Bg, ktA, 1, PBw); }
        sync_open(); mfma_lo(bv[1]); sync_close();
        // ---- Phase 3: P m1 s0; stage B(ktA){2,3} -> P.B
        load_av(PA, 1, 0);
        if (more) { stage(Bg, ktA, 2, PBw); stage(Bg, ktA, 3, PBw); }
        sync_open(); mfma_hi(bv[0]); sync_close();
        // ---- Phase 4: P m1 s1; stage A(ktA){0,2} -> P.A half0 (freed at Ph2);
        //      then counted vmcnt so Q is ready behind the closing barrier
        load_av(PA, 1, 1);
        if (more) { stage(Ag, ktA, 0, PAw); stage(Ag, ktA, 2, PAw); }
        sync_open(); mfma_hi(bv[1]);
        __builtin_amdgcn_sched_barrier(0);
        if (more) asm volatile("s_waitcnt vmcnt(6)" ::: "memory");
        else      asm volatile("s_waitcnt vmcnt(0)" ::: "memory");
        sync_close();
        // ---- Phase 5: Q m0 s0; bv <- Q.B; stage A(ktA){1,3} -> P.A half1 (freed at Ph4)
        load_bv(QB);
        load_av(QA, 0, 0);
        if (more) { stage(Ag, ktA, 1, PAw); stage(Ag, ktA, 3, PAw); }
        sync_open(); mfma_lo(bv[0]); sync_close();
        // ---- Phase 6: Q m0 s1; stage B(ktB){0,1} -> Q.B (freed at Ph5)
        load_av(QA, 0, 1);
        if (more) { stage(Bg, ktB, 0, QBw); stage(Bg, ktB, 1, QBw); }
        sync_open(); mfma_lo(bv[1]); sync_close();
        // ---- Phase 7: Q m1 s0; stage B(ktB){2,3} -> Q.B
        load_av(QA, 1, 0);
        if (more) { stage(Bg, ktB, 2, QBw); stage(Bg, ktB, 3, QBw); }
        sync_open(); mfma_hi(bv[0]); sync_close();
        // ---- Phase 8: Q m1 s1; stage A(ktB){0,2} -> Q.A half0 (freed at Ph6);
        //      counted vmcnt so next P is ready behind the closing barrier
        load_av(QA, 1, 1);
        if (more) { stage(Ag, ktB, 0, QAw); stage(Ag, ktB, 2, QAw); }
        sync_open(); mfma_hi(bv[1]);
        __builtin_amdgcn_sched_barrier(0);
        if (more) asm volatile("s_waitcnt vmcnt(6)" ::: "memory");
        sync_close();
    }
}

// ---------------------------------------------------------------- GEMM1: bf16 out
__global__ __launch_bounds__(512) void gemm256_b16(const unsigned short* __restrict__ A,
                                                   const unsigned short* __restrict__ Bt,
                                                   unsigned short* __restrict__ C,
                                                   int N, int K, int ntN) {
    extern __shared__ unsigned short smem_us[];
    const int tid = threadIdx.x, lane = tid & 63, w = tid >> 6;
    const int col = lane & 15, quad = lane >> 4;
    const int wm = (w >> 2) * 128, wn = (w & 3) * 64;
    // XCD-chunked bijective swizzle (gridDim.x % 8 == 0)
    const int bid = blockIdx.x;
    const int qch = gridDim.x >> 3;
    const int swb = (bid & 7) * qch + (bid >> 3);
    const int mt = swb / ntN, ntl = swb - mt * ntN;
    const int m0 = mt * 256, n0 = ntl * 256;

    f32x4 acc[8][4];
    gemm256_mainloop(A, Bt, K, m0, n0, smem_us, acc);

    // epilogue: per-wave LDS repack (reuses smem; all waves past final barrier)
    float* Tw = (float*)smem_us + w * 336;
    const int t2 = lane >> 2, n4 = (lane & 3) * 4;
#pragma unroll
    for (int ri = 0; ri < 8; ++ri)
#pragma unroll
        for (int cj = 0; cj < 4; ++cj) {
#pragma unroll
            for (int r = 0; r < 4; ++r)
                Tw[(quad * 4 + r) * 20 + col] = acc[ri][cj][r];
            float4 v = *(const float4*)&Tw[t2 * 20 + n4];
            ushort4 o;
            o.x = f2bf(v.x); o.y = f2bf(v.y); o.z = f2bf(v.z); o.w = f2bf(v.w);
            *(ushort4*)(C + (size_t)(m0 + wm + ri * 16 + t2) * N + n0 + wn + cj * 16 + n4) = o;
        }
}

// ---------------------------------------------------------------- GEMM2: attn @ Wo, fp32 transposed out
__global__ __launch_bounds__(512) void gemm256_out(const unsigned short* __restrict__ A,
                                                   const unsigned short* __restrict__ Bt,
                                                   float* __restrict__ out,
                                                   int N, int K, int ntN) {
    extern __shared__ unsigned short smem_us[];
    const int tid = threadIdx.x, lane = tid & 63, w = tid >> 6;
    const int col = lane & 15, quad = lane >> 4;
    const int wm = (w >> 2) * 128, wn = (w & 3) * 64;
    const int bid = blockIdx.x;
    const int qch = gridDim.x >> 3;
    const int swb = (bid & 7) * qch + (bid >> 3);
    const int mt = swb / ntN, ntl = swb - mt * ntN;
    const int m0 = mt * 256, n0 = ntl * 256;

    f32x4 acc[8][4];
    gemm256_mainloop(A, Bt, K, m0, n0, smem_us, acc);

    // epilogue: transpose per 16x16 fragment in per-wave LDS, store out[n][t] coalesced
    const int b = m0 >> 12, t0 = m0 & 4095;
    float* dst = out + (size_t)b * (kIn + kE) * kT + (size_t)kIn * kT;
    float* Tw = (float*)smem_us + w * 336;
    const int n2 = lane >> 2, t4 = (lane & 3) * 4;
#pragma unroll
    for (int ri = 0; ri < 8; ++ri)
#pragma unroll
        for (int cj = 0; cj < 4; ++cj) {
            *(float4*)&Tw[col * 20 + quad * 4] =
                (float4){acc[ri][cj][0], acc[ri][cj][1], acc[ri][cj][2], acc[ri][cj][3]};
            float4 v = *(const float4*)&Tw[n2 * 20 + t4];
            *(float4*)(dst + (size_t)(n0 + wn + cj * 16 + n2) * kT + t0 + wm + ri * 16 + t4) = v;
        }
}

// ---------------------------------------------------------------- Phase A (MFMA): KV, Ksum
__global__ __launch_bounds__(256) void phaseA_mfma(const unsigned short* __restrict__ QKVb,
                                                   const unsigned short* __restrict__ projb,
                                                   float* __restrict__ KVg,
                                                   float* __restrict__ Ksumg) {
    __shared__ unsigned short Ks[64 * 64];     // [t][d] XOR-swizzled chunks
    __shared__ unsigned short VT[64 * 72];     // [d][t] pad 8
    __shared__ unsigned short KpT[256 * 72];   // [f][t] pad 8
    const int tid = threadIdx.x, lane = tid & 63, w = tid >> 6;
    const int col = lane & 15, quad = lane >> 4;
    const int bh = blockIdx.x, b = bh >> 4, h = bh & 15;
    const int grp = blockIdx.y;
    const int f0 = w * 64;
    const int swz = col & 7;

    bf16x8 bB[2][4];   // proj B-fragments, invariant
#pragma unroll
    for (int s = 0; s < 2; ++s)
#pragma unroll
        for (int j = 0; j < 4; ++j)
            bB[s][j] = *(const bf16x8*)(projb + (size_t)(f0 + j * 16 + col) * 64 + s * 32 + quad * 8);

    f32x4 kvacc[4][4];
#pragma unroll
    for (int i = 0; i < 4; ++i)
#pragma unroll
        for (int j = 0; j < 4; ++j) kvacc[i][j] = (f32x4){0.f, 0.f, 0.f, 0.f};
    float ksum_acc[4] = {0.f, 0.f, 0.f, 0.f};

    for (int it = 0; it < 8; ++it) {
        const size_t rowbase = (size_t)(b * kT + grp * 512 + it * 64) * kQKVs + h * kD;
        __syncthreads();
#pragma unroll
        for (int i2 = 0; i2 < 2; ++i2) {
            int p = (i2 * 4 + w) * 64 + lane;
            int row = p >> 3;
            int cg = ((p & 7) ^ (row & 7)) * 8;
            gload_lds16(QKVb + rowbase + 1024 + (size_t)row * kQKVs + cg, &Ks[(i2 * 4 + w) * 512]);
        }
#pragma unroll
        for (int r = 0; r < 4; ++r) {
            int lin = r * 256 + tid;
            int t = lin >> 4, d4 = (lin & 15) * 4;
            ushort4 v = *(const ushort4*)(QKVb + rowbase + 2048 + (size_t)t * kQKVs + d4);
            VT[(d4 + 0) * 72 + t] = v.x; VT[(d4 + 1) * 72 + t] = v.y;
            VT[(d4 + 2) * 72 + t] = v.z; VT[(d4 + 3) * 72 + t] = v.w;
        }
        __syncthreads();
        bf16x8 av[2][4];
#pragma unroll
        for (int s = 0; s < 2; ++s)
#pragma unroll
            for (int i = 0; i < 4; ++i)
                av[s][i] = *(const bf16x8*)&Ks[(i * 16 + col) * 64 + ((s * 4 + quad) ^ swz) * 8];
#pragma unroll
        for (int j = 0; j < 4; ++j) {
            f32x4 sa[4];
#pragma unroll
            for (int i = 0; i < 4; ++i) sa[i] = (f32x4){0.f, 0.f, 0.f, 0.f};
#pragma unroll
            for (int s = 0; s < 2; ++s)
#pragma unroll
                for (int i = 0; i < 4; ++i)
                    sa[i] = __builtin_amdgcn_mfma_f32_16x16x32_bf16(av[s][i], bB[s][j], sa[i], 0, 0, 0);
            const int f = f0 + j * 16 + col;
#pragma unroll
            for (int i = 0; i < 4; ++i) {
                float e0 = __expf(sa[i][0]) + 1e-6f;
                float e1 = __expf(sa[i][1]) + 1e-6f;
                float e2 = __expf(sa[i][2]) + 1e-6f;
                float e3 = __expf(sa[i][3]) + 1e-6f;
                ksum_acc[j] += (e0 + e1) + (e2 + e3);
                ushort4 pk;
                pk.x = f2bf(e0); pk.y = f2bf(e1); pk.z = f2bf(e2); pk.w = f2bf(e3);
                *(ushort4*)&KpT[f * 72 + i * 16 + quad * 4] = pk;
            }
        }
#pragma unroll
        for (int s = 0; s < 2; ++s) {
            const int kc = s * 32 + quad * 8;
            bf16x8 a2[4], b2[4];
#pragma unroll
            for (int i = 0; i < 4; ++i)
                a2[i] = *(const bf16x8*)&KpT[(f0 + i * 16 + col) * 72 + kc];
#pragma unroll
            for (int jn = 0; jn < 4; ++jn)
                b2[jn] = *(const bf16x8*)&VT[(jn * 16 + col) * 72 + kc];
#pragma unroll
            for (int i = 0; i < 4; ++i)
#pragma unroll
                for (int jn = 0; jn < 4; ++jn)
                    kvacc[i][jn] = __builtin_amdgcn_mfma_f32_16x16x32_bf16(a2[i], b2[jn], kvacc[i][jn], 0, 0, 0);
        }
    }
    const size_t kvbase = (size_t)bh * (kF * kD);
#pragma unroll
    for (int i = 0; i < 4; ++i)
#pragma unroll
        for (int jn = 0; jn < 4; ++jn)
#pragma unroll
            for (int r = 0; r < 4; ++r)
                atomicAdd(&KVg[kvbase + (size_t)(f0 + i * 16 + quad * 4 + r) * kD + jn * 16 + col],
                          kvacc[i][jn][r]);
#pragma unroll
    for (int j = 0; j < 4; ++j) {
        float v = ksum_acc[j];
        v += __shfl_xor(v, 16);
        v += __shfl_xor(v, 32);
        if (quad == 0) atomicAdd(&Ksumg[(size_t)bh * kF + f0 + j * 16 + col], v);
    }
}

// ---------------------------------------------------------------- Phase B (MFMA): attn bf16
__global__ __launch_bounds__(256) void phaseB_mfma(const unsigned short* __restrict__ QKVb,
                                                   const unsigned short* __restrict__ projb,
                                                   const unsigned short* __restrict__ KVTb,
                                                   const float* __restrict__ Ksumg,
                                                   unsigned short* __restrict__ attnb) {
    __shared__ unsigned short Qs[64 * 64];      // [t][d] XOR-swizzled chunks
    __shared__ unsigned short Qp[64 * 264];     // [t][f] pad 8
    __shared__ unsigned short KVTs[64 * 264];   // [d][f] pad 8
    __shared__ float KsS[256];
    __shared__ float denp[4][64];
    const int tid = threadIdx.x, lane = tid & 63, w = tid >> 6;
    const int col = lane & 15, quad = lane >> 4;
    const int bh = blockIdx.x, b = bh >> 4, h = bh & 15;
    const int grp = blockIdx.y;
    const int f0 = w * 64;
    const int swz = col & 7;

    bf16x8 bB[2][4];
#pragma unroll
    for (int s = 0; s < 2; ++s)
#pragma unroll
        for (int j = 0; j < 4; ++j)
            bB[s][j] = *(const bf16x8*)(projb + (size_t)(f0 + j * 16 + col) * 64 + s * 32 + quad * 8);

#pragma unroll
    for (int r = 0; r < 8; ++r) {
        int lin = r * 256 + tid;
        int d = lin >> 5, fc8 = (lin & 31) * 8;
        *(bf16x8*)&KVTs[d * 264 + fc8] = *(const bf16x8*)(KVTb + (size_t)bh * 16384 + d * 256 + fc8);
    }
    KsS[tid] = Ksumg[(size_t)bh * kF + tid];

    for (int it = 0; it < 8; ++it) {
        const int tg0 = grp * 512 + it * 64;
        const size_t rowbase = (size_t)(b * kT + tg0) * kQKVs + h * kD;
        __syncthreads();
#pragma unroll
        for (int i2 = 0; i2 < 2; ++i2) {
            int p = (i2 * 4 + w) * 64 + lane;
            int row = p >> 3;
            int cg = ((p & 7) ^ (row & 7)) * 8;
            gload_lds16(QKVb + rowbase + (size_t)row * kQKVs + cg, &Qs[(i2 * 4 + w) * 512]);
        }
        __syncthreads();
        bf16x8 av[2][4];
#pragma unroll
        for (int s = 0; s < 2; ++s)
#pragma unroll
            for (int i = 0; i < 4; ++i)
                av[s][i] = *(const bf16x8*)&Qs[(i * 16 + col) * 64 + ((s * 4 + quad) ^ swz) * 8];
#pragma unroll
        for (int j = 0; j < 4; ++j) {
            f32x4 sa[4];
#pragma unroll
            for (int i = 0; i < 4; ++i) sa[i] = (f32x4){0.f, 0.f, 0.f, 0.f};
#pragma unroll
            for (int s = 0; s < 2; ++s)
#pragma unroll
                for (int i = 0; i < 4; ++i)
                    sa[i] = __builtin_amdgcn_mfma_f32_16x16x32_bf16(av[s][i], bB[s][j], sa[i], 0, 0, 0);
            const int f = f0 + j * 16 + col;
#pragma unroll
            for (int i = 0; i < 4; ++i) {
                const int tb = i * 16 + quad * 4;
                Qp[(tb + 0) * 264 + f] = f2bf(__expf(sa[i][0]) + 1e-6f);
                Qp[(tb + 1) * 264 + f] = f2bf(__expf(sa[i][1]) + 1e-6f);
                Qp[(tb + 2) * 264 + f] = f2bf(__expf(sa[i][2]) + 1e-6f);
                Qp[(tb + 3) * 264 + f] = f2bf(__expf(sa[i][3]) + 1e-6f);
            }
        }
        float dp = 0.f;
#pragma unroll
        for (int u = 0; u < 64; u += 8) {
            bf16x8 qv = *(const bf16x8*)&Qp[lane * 264 + f0 + u];
#pragma unroll
            for (int k2 = 0; k2 < 8; ++k2)
                dp += bf2f((unsigned short)qv[k2]) * KsS[f0 + u + k2];
        }
        denp[w][lane] = dp;
        __syncthreads();
        f32x4 nacc[4];
#pragma unroll
        for (int jn = 0; jn < 4; ++jn) nacc[jn] = (f32x4){0.f, 0.f, 0.f, 0.f};
#pragma unroll
        for (int s = 0; s < 8; ++s) {
            const int kc = s * 32 + quad * 8;
            bf16x8 aq = *(const bf16x8*)&Qp[(w * 16 + col) * 264 + kc];
#pragma unroll
            for (int jn = 0; jn < 4; ++jn) {
                bf16x8 bk = *(const bf16x8*)&KVTs[(jn * 16 + col) * 264 + kc];
                nacc[jn] = __builtin_amdgcn_mfma_f32_16x16x32_bf16(aq, bk, nacc[jn], 0, 0, 0);
            }
        }
#pragma unroll
        for (int r = 0; r < 4; ++r) {
            const int tl = w * 16 + quad * 4 + r;
            float den = denp[0][tl] + denp[1][tl] + denp[2][tl] + denp[3][tl];
            float rd = 1.f / fmaxf(den, 1e-6f);
            const size_t ob = (size_t)(b * kT + tg0 + tl) * kE + h * kD;
#pragma unroll
            for (int jn = 0; jn < 4; ++jn)
                attnb[ob + jn * 16 + col] = f2bf(nacc[jn][r] * rd);
        }
    }
}

// ---------------------------------------------------------------- launch
extern "C" void kernel_launch(void* const* d_in, const int* in_sizes, int n_in,
                              void* d_out, int out_size, void* d_ws, size_t ws_size,
                              hipStream_t stream) {
    (void)in_sizes; (void)n_in; (void)out_size; (void)ws_size;
    const float* x    = (const float*)d_in[0];
    const float* Wq   = (const float*)d_in[1];
    const float* Wk   = (const float*)d_in[2];
    const float* Wv   = (const float*)d_in[3];
    const float* Wo   = (const float*)d_in[4];
    const float* proj = (const float*)d_in[5];
    float* out = (float*)d_out;

    static int attr_done = 0;
    if (!attr_done) {
        hipFuncSetAttribute((const void*)gemm256_b16,
                            hipFuncAttributeMaxDynamicSharedMemorySize, 131072);
        hipFuncSetAttribute((const void*)gemm256_out,
                            hipFuncAttributeMaxDynamicSharedMemorySize, 131072);
        attr_done = 1;
    }

    char* ws = (char*)d_ws;
    unsigned short* QKVb  = (unsigned short*)(ws);               // 96MB
    unsigned short* attnb = (unsigned short*)(ws + 100663296);   // 32MB
    unsigned short* Abuf  = (unsigned short*)(ws + 100663296);   // aliases attnb (pre-gemm1)
    unsigned short* Btqkv = (unsigned short*)(ws + 134217728);   // 3MB
    unsigned short* WoT   = (unsigned short*)(ws + 137363456);   // 2MB
    unsigned short* projb = (unsigned short*)(ws + 139460608);   // 32KB
    float*          KVg   = (float*)(ws + 139493376);            // 4MB
    float*          Ksumg = (float*)(ws + 143687680);            // 64KB
    unsigned short* KVTb  = (unsigned short*)(ws + 143753216);   // 2MB

    copy_x_kernel<<<dim3(8192), 256, 0, stream>>>(x, out);

    trans_f2b_kernel<<<dim3(64, 8, 4), 256, 0, stream>>>(x, Abuf, kIn, kT,
                                                         (long)kIn * kT, (long)kT * kIn);
    trans_qkv_kernel<<<dim3(16, 8, 3), 256, 0, stream>>>(Wq, Wk, Wv, Btqkv);
    trans_f2b_kernel<<<dim3(16, 16, 1), 256, 0, stream>>>(Wo, WoT, kE, kE, 0, 0);
    f2b_flat_kernel<<<dim3(16), 256, 0, stream>>>(proj, projb, kF * kD / 4);

    // GEMM1: M=16384 x N=3072, K=512 -> 64 x 12 = 768 tiles
    gemm256_b16<<<dim3(768), 512, 131072, stream>>>(Abuf, Btqkv, QKVb, kQKVs, kIn, 12);

    const int nz = kB * kH * kF * kD + kB * kH * kF;
    zero_kernel<<<dim3((nz + 255) / 256), 256, 0, stream>>>(KVg, nz);

    phaseA_mfma<<<dim3(64, 8), 256, 0, stream>>>(QKVb, projb, KVg, Ksumg);
    trans_f2b_kernel<<<dim3(1, 4, 64), 256, 0, stream>>>(KVg, KVTb, kF, kD,
                                                         (long)kF * kD, (long)kF * kD);
    phaseB_mfma<<<dim3(64, 8), 256, 0, stream>>>(QKVb, projb, KVTb, Ksumg, attnb);

    // GEMM2: M=16384 x N=1024, K=1024 -> 64 x 4 = 256 tiles
    gemm256_out<<<dim3(256), 512, 131072, stream>>>(attnb, WoT, out, kE, kE, 4);
}